// Round 15
// baseline (118.045 us; speedup 1.0000x reference)
//
#include <hip/hip_runtime.h>
#include <hip/hip_bf16.h>

// GRIN MoE feed-forward, routed top-2, bf16 MFMA grouped GEMM.
// T=4096 tokens, H=512, F=1024, E=8.
// R1 counting-sort routing. R2 gload_lds. R3 counted-vmcnt 3-buffer + swizzle.
// R7 fused pre. R9 expert-contiguous XCD map. R12 fused memset. R14 K-panel-major.
// R15: F-split GEMM pipeline: g1a | (g1b || g2a) | g2b — gemm2's K == gemm1's N,
//      so the halves are independent and overlap inside one kernel with NO
//      ordering assumptions (disjoint hbuf panels; stream orders K1->K2).

#define T_TOK 4096
#define HDIM  512
#define FDIM  1024
#define NEXP  8
#define MAXT1 72
#define SLOTP 8320

typedef __attribute__((ext_vector_type(8))) __bf16 bf16x8;
typedef __attribute__((ext_vector_type(4))) float  f32x4;
typedef unsigned short ushort_t;

__device__ __forceinline__ unsigned int f2bf(float f) {
  __hip_bfloat16 h = __float2bfloat16(f);
  return (unsigned int)__builtin_bit_cast(unsigned short, h);
}

__device__ __forceinline__ void gload16(const ushort_t* g, ushort_t* l) {
  __builtin_amdgcn_global_load_lds(
      (const __attribute__((address_space(1))) unsigned int*)g,
      (__attribute__((address_space(3))) unsigned int*)l, 16, 0, 0);
}

// --- fused pre: gating (0..1023) + transconv (1024..13311) + zero-out (rest) --
__global__ void pre_kernel(const float* __restrict__ x, const float* __restrict__ wg,
                           const float* __restrict__ bg, int4* __restrict__ selraw,
                           ushort_t* __restrict__ xbuf,
                           const float* __restrict__ w1, const float* __restrict__ w3,
                           const float* __restrict__ w2, ushort_t* __restrict__ w1p,
                           ushort_t* __restrict__ w3p, ushort_t* __restrict__ w2p,
                           float* __restrict__ outz) {
  __shared__ float tile[32][33];
  int blk = blockIdx.x;
  if (blk >= 13312) {
    int i = (blk - 13312) * 1024 + threadIdx.x * 4;
    *reinterpret_cast<float4*>(outz + i) = make_float4(0.f, 0.f, 0.f, 0.f);
    return;
  }
  if (blk < 1024) {
    int wv = threadIdx.x >> 6;
    int lane = threadIdx.x & 63;
    int t = blk * 4 + wv;
    const float* xr = x + (size_t)t * HDIM + lane * 8;
    float4 xa = *reinterpret_cast<const float4*>(xr);
    float4 xb = *reinterpret_cast<const float4*>(xr + 4);
    uint4 o;
    o.x = f2bf(xa.x) | (f2bf(xa.y) << 16);
    o.y = f2bf(xa.z) | (f2bf(xa.w) << 16);
    o.z = f2bf(xb.x) | (f2bf(xb.y) << 16);
    o.w = f2bf(xb.z) | (f2bf(xb.w) << 16);
    *reinterpret_cast<uint4*>(xbuf + (size_t)t * HDIM + lane * 8) = o;

    float xv[8] = {xa.x, xa.y, xa.z, xa.w, xb.x, xb.y, xb.z, xb.w};
    float acc[8];
#pragma unroll
    for (int e = 0; e < 8; e++) acc[e] = 0.f;
    int h0 = lane * 8;
#pragma unroll
    for (int j = 0; j < 8; j++) {
      const float4* wr = reinterpret_cast<const float4*>(wg + (size_t)(h0 + j) * 8);
      float4 w0 = wr[0], w1v = wr[1];
      float xj = xv[j];
      acc[0] += xj * w0.x; acc[1] += xj * w0.y; acc[2] += xj * w0.z; acc[3] += xj * w0.w;
      acc[4] += xj * w1v.x; acc[5] += xj * w1v.y; acc[6] += xj * w1v.z; acc[7] += xj * w1v.w;
    }
#pragma unroll
    for (int s = 32; s >= 1; s >>= 1) {
#pragma unroll
      for (int e = 0; e < 8; e++) acc[e] += __shfl_xor(acc[e], s, 64);
    }
    if (lane == 0) {
      float sc[8];
      float mx = -1e30f;
      for (int e = 0; e < 8; e++) { sc[e] = acc[e] + bg[e]; mx = fmaxf(mx, sc[e]); }
      float sum = 0.f;
      for (int e = 0; e < 8; e++) { sc[e] = expf(sc[e] - mx); sum += sc[e]; }
      for (int e = 0; e < 8; e++) sc[e] /= sum;
      int s1 = 0; float mx1 = sc[0];
      for (int e = 1; e < 8; e++) if (sc[e] > mx1) { mx1 = sc[e]; s1 = e; }
      float den1 = 0.f;
      for (int e = 0; e < 8; e++)
        if (!((mx1 - sc[e]) / mx1 > 0.02f)) den1 += expf(sc[e] - mx1);
      float mult1 = 1.0f / den1;
      int s2 = 0; float mx2 = -1e30f;
      for (int e = 0; e < 8; e++) if (e != s1 && sc[e] > mx2) { mx2 = sc[e]; s2 = e; }
      float den2 = 0.f;
      for (int e = 0; e < 8; e++) {
        if (e == s1) continue;
        float fac = fmaxf(sc[e], mx2);
        if (!((mx2 - sc[e]) / fac > 0.02f)) den2 += expf(sc[e] - mx2);
      }
      float mult2 = 1.0f / den2;
      selraw[t] = make_int4(s1, s2, __float_as_int(mult1), __float_as_int(mult2));
    }
    return;
  }
  int b = blk - 1024;
  const float* src; ushort_t* dst; int R, C, rt, ct, e;
  if (b < 8192) {
    src = (b < 4096) ? w1 : w3; dst = (b < 4096) ? w1p : w3p;
    int r = b & 4095; e = r >> 9; r &= 511;
    R = HDIM; C = FDIM; rt = r >> 5; ct = r & 31;
  } else {
    src = w2; dst = w2p;
    int r = b - 8192; e = r >> 9; r &= 511;
    R = FDIM; C = HDIM; rt = r >> 4; ct = r & 15;
  }
  int rb = rt * 32, cb = ct * 32;
  int tr = threadIdx.x >> 3, tc = (threadIdx.x & 7) * 4;
  const float* s = src + ((size_t)e * R + rb + tr) * C + cb + tc;
  float4 v = *reinterpret_cast<const float4*>(s);
  tile[tc + 0][tr] = v.x; tile[tc + 1][tr] = v.y;
  tile[tc + 2][tr] = v.z; tile[tc + 3][tr] = v.w;
  __syncthreads();
  ushort4 ov = {(ushort_t)f2bf(tile[tr][tc]), (ushort_t)f2bf(tile[tr][tc + 1]),
                (ushort_t)f2bf(tile[tr][tc + 2]), (ushort_t)f2bf(tile[tr][tc + 3])};
  size_t da = (((size_t)e * (R >> 5) + (rb >> 5)) * C + cb + tr) * 32 + tc;
  *reinterpret_cast<ushort4*>(dst + da) = ov;
}

// ------- build: counting sort -> slot2tok / wtls + schedule ------------------
__global__ __launch_bounds__(256) void build_kernel(
    const int4* __restrict__ selraw, int* __restrict__ cnt, int* __restrict__ offs,
    int2* __restrict__ sched1, int* __restrict__ slot2tok, float* __restrict__ wtls) {
  __shared__ int scan[256][8];
  __shared__ int loc[256][8];
  __shared__ int offs_sh[8];
  int tid = threadIdx.x;
#pragma unroll
  for (int e = 0; e < 8; e++) { scan[tid][e] = 0; loc[tid][e] = 0; }
  int t0 = tid * (T_TOK / 256);
  int4 raw[T_TOK / 256];
#pragma unroll
  for (int i = 0; i < T_TOK / 256; i++) {
    raw[i] = selraw[t0 + i];
    loc[tid][raw[i].x]++;
    loc[tid][raw[i].y]++;
  }
#pragma unroll
  for (int e = 0; e < 8; e++) scan[tid][e] = loc[tid][e];
  __syncthreads();
  for (int s = 1; s < 256; s <<= 1) {
    int v[8];
    if (tid >= s) {
#pragma unroll
      for (int e = 0; e < 8; e++) v[e] = scan[tid - s][e];
    }
    __syncthreads();
    if (tid >= s) {
#pragma unroll
      for (int e = 0; e < 8; e++) scan[tid][e] += v[e];
    }
    __syncthreads();
  }
  if (tid == 0) {
    int a = 0, t1 = 0;
    for (int e = 0; e < 8; e++) {
      int ce = scan[255][e];
      cnt[e] = ce; offs[e] = a; offs_sh[e] = a; a += ce;
    }
    for (int e = 0; e < 8; e++)
      for (int b = 0; b < scan[255][e]; b += 128) sched1[t1++] = make_int2(e, b);
    for (; t1 < MAXT1; t1++) sched1[t1] = make_int2(-1, 0);
  }
#pragma unroll
  for (int e = 0; e < 8; e++) scan[tid][e] -= loc[tid][e];
  __syncthreads();
#pragma unroll
  for (int i = 0; i < T_TOK / 256; i++) {
    int t = t0 + i;
    int s1 = raw[i].x, s2 = raw[i].y;
    int p1 = scan[tid][s1]++;
    int sl1 = offs_sh[s1] + p1;
    slot2tok[sl1] = t; wtls[sl1] = __int_as_float(raw[i].z);
    int p2 = scan[tid][s2]++;
    int sl2 = offs_sh[s2] + p2;
    slot2tok[sl2] = t; wtls[sl2] = __int_as_float(raw[i].w);
  }
}

// ------- xgather: xslot[kc][slot][32] = xb[slot2tok[slot]][kc*32..] ----------
__global__ void xgather_kernel(const ushort_t* __restrict__ xb,
                               const int* __restrict__ slot2tok,
                               ushort_t* __restrict__ xslot) {
  int gid = blockIdx.x * 256 + threadIdx.x;
  int slot = gid & 8191;
  int kc = gid >> 13;
  int tok = slot2tok[slot];
  const uint4* s = reinterpret_cast<const uint4*>(xb + (size_t)tok * HDIM + kc * 32);
  uint4* d = reinterpret_cast<uint4*>(xslot + ((size_t)kc * SLOTP + slot) * 32);
  d[0] = s[0]; d[1] = s[1]; d[2] = s[2]; d[3] = s[3];
}

// ---------------- GEMM1 tile body (one mt x nb, 128x128xK512) ---------------
// sm layout: Xs = sm[buf*4096], W1s = sm[12288 + buf*4096], W3s = sm[24576 + buf*4096]
#define STG1(b, kc) do { \
    gload16(gx  + (size_t)(kc) * (SLOTP * 32), &sm[(b) * 4096 + (wv * 64 + lane) * 8]); \
    gload16(gw1 + (size_t)(kc) * (FDIM * 32),  &sm[12288 + (b) * 4096 + (wv * 64 + lane) * 8]); \
    gload16(gw3 + (size_t)(kc) * (FDIM * 32),  &sm[24576 + (b) * 4096 + (wv * 64 + lane) * 8]); \
  } while (0)

__device__ __forceinline__ void gemm1_tile(
    int mt, int nb, ushort_t* sm,
    const ushort_t* __restrict__ xslot, const ushort_t* __restrict__ w1p,
    const ushort_t* __restrict__ w3p, const float* __restrict__ wtls,
    const int* __restrict__ cnt, const int* __restrict__ offs,
    const int2* __restrict__ sched, ushort_t* __restrict__ hbufp) {
  __shared__ float wtl_sh[128];
  int2 sc = sched[mt];
  if (sc.x < 0) return;
  int e = sc.x, base = sc.y;
  int cnte = cnt[e], off0 = offs[e];
  int rows = min(128, cnte - base);
  int sb = off0 + base;
  int n0 = nb * 128;
  int tid = threadIdx.x;
  if (tid < 128) wtl_sh[tid] = (tid < rows) ? wtls[sb + tid] : 0.f;
  int lane = tid & 63, wv = tid >> 6;
  int wm = (wv >> 2) * 64, wn = (wv & 3) * 32;

  int rS = wv * 16 + (lane >> 2);
  int swz = ((lane & 3) ^ ((rS >> 1) & 3)) * 8;
  const ushort_t* gx  = xslot + ((size_t)(sb + rS)) * 32 + swz;
  const ushort_t* gw1 = w1p + (((size_t)e * 16) * FDIM + n0 + rS) * 32 + swz;
  const ushort_t* gw3 = w3p + (((size_t)e * 16) * FDIM + n0 + rS) * 32 + swz;

  f32x4 accU[4][2], accV[4][2];
#pragma unroll
  for (int m = 0; m < 4; m++)
#pragma unroll
    for (int n = 0; n < 2; n++) {
      accU[m][n] = {0.f, 0.f, 0.f, 0.f};
      accV[m][n] = {0.f, 0.f, 0.f, 0.f};
    }

  STG1(0, 0);
  STG1(1, 1);

  int uc = lane >> 4;
#pragma unroll
  for (int t = 0; t < 16; t++) {
    if (t < 15) asm volatile("s_waitcnt vmcnt(3)" ::: "memory");
    else        asm volatile("s_waitcnt vmcnt(0)" ::: "memory");
    __builtin_amdgcn_s_barrier();
    __builtin_amdgcn_sched_barrier(0);
    if (t < 14) STG1((t + 2) % 3, t + 2);
    const int cur = t % 3;
    bf16x8 a[4], bu[2], bv[2];
#pragma unroll
    for (int m = 0; m < 4; m++) {
      int r = wm + m * 16 + (lane & 15);
      a[m] = __builtin_bit_cast(bf16x8,
          *reinterpret_cast<const uint4*>(&sm[(cur) * 4096 + (r * 4 + (uc ^ ((r >> 1) & 3))) * 8]));
    }
#pragma unroll
    for (int n = 0; n < 2; n++) {
      int r = wn + n * 16 + (lane & 15);
      bu[n] = __builtin_bit_cast(bf16x8,
          *reinterpret_cast<const uint4*>(&sm[12288 + (cur) * 4096 + (r * 4 + (uc ^ ((r >> 1) & 3))) * 8]));
      bv[n] = __builtin_bit_cast(bf16x8,
          *reinterpret_cast<const uint4*>(&sm[24576 + (cur) * 4096 + (r * 4 + (uc ^ ((r >> 1) & 3))) * 8]));
    }
#pragma unroll
    for (int m = 0; m < 4; m++)
#pragma unroll
      for (int n = 0; n < 2; n++) {
        accU[m][n] = __builtin_amdgcn_mfma_f32_16x16x32_bf16(a[m], bu[n], accU[m][n], 0, 0, 0);
        accV[m][n] = __builtin_amdgcn_mfma_f32_16x16x32_bf16(a[m], bv[n], accV[m][n], 0, 0, 0);
      }
  }

#pragma unroll
  for (int m = 0; m < 4; m++) {
#pragma unroll
    for (int rr = 0; rr < 4; rr++) {
      int row = wm + m * 16 + ((lane >> 4) << 2) + rr;
      if (row < rows) {
        float wgt = wtl_sh[row];
        int slot = sb + row;
#pragma unroll
        for (int n = 0; n < 2; n++) {
          int f = n0 + wn + n * 16 + (lane & 15);
          float u = accU[m][n][rr], v = accV[m][n][rr];
          float h = 0.5f * u * (1.0f + erff(u * 0.707106781186547524f)) * v * wgt;
          hbufp[((size_t)(f >> 5) * SLOTP + slot) * 32 + (f & 31)] = (ushort_t)f2bf(h);
        }
      }
    }
  }
}

// ---------------- GEMM2 half-K tile body (one mt x nb, 128x128xK512) ---------
// sm layout: As = sm[buf*4096], Bs = sm[12288 + buf*4096]
#define STG2(b, kc) do { \
    gload16(ga + (size_t)(kc) * (SLOTP * 32), &sm[(b) * 4096 + (wv * 64 + lane) * 8]); \
    gload16(gb + (size_t)(kc) * (HDIM * 32),  &sm[12288 + (b) * 4096 + (wv * 64 + lane) * 8]); \
  } while (0)

template<int KBASE>
__device__ __forceinline__ void gemm2_tile(
    int mt, int nb, ushort_t* sm,
    const ushort_t* __restrict__ hbufp, const ushort_t* __restrict__ w2p,
    const int* __restrict__ slot2tok, const int* __restrict__ cnt,
    const int* __restrict__ offs, const int2* __restrict__ sched,
    float* __restrict__ out) {
  __shared__ int toks[128];
  int2 sc = sched[mt];
  if (sc.x < 0) return;
  int e = sc.x, base = sc.y;
  int cnte = cnt[e], off0 = offs[e];
  int rows = min(128, cnte - base);
  int sb = off0 + base;
  int n0 = nb * 128;
  int tid = threadIdx.x;
  if (tid < 128) toks[tid] = slot2tok[sb + min(tid, rows - 1)];
  int lane = tid & 63, wv = tid >> 6;
  int wm = (wv >> 2) * 64, wn = (wv & 3) * 32;
  __syncthreads();

  int rS = wv * 16 + (lane >> 2);
  int swz = ((lane & 3) ^ ((rS >> 1) & 3)) * 8;
  const ushort_t* ga = hbufp + (((size_t)KBASE) * (SLOTP * 32)) + ((size_t)(sb + rS)) * 32 + swz;
  const ushort_t* gb = w2p + (((size_t)e * 32 + KBASE) * HDIM + n0 + rS) * 32 + swz;

  f32x4 acc[4][2];
#pragma unroll
  for (int m = 0; m < 4; m++)
#pragma unroll
    for (int n = 0; n < 2; n++) acc[m][n] = {0.f, 0.f, 0.f, 0.f};

  STG2(0, 0);
  STG2(1, 1);

  int uc = lane >> 4;
#pragma unroll
  for (int t = 0; t < 16; t++) {
    if (t < 15) asm volatile("s_waitcnt vmcnt(2)" ::: "memory");
    else        asm volatile("s_waitcnt vmcnt(0)" ::: "memory");
    __builtin_amdgcn_s_barrier();
    __builtin_amdgcn_sched_barrier(0);
    if (t < 14) STG2((t + 2) % 3, t + 2);
    const int cur = t % 3;
    bf16x8 a[4], b[2];
#pragma unroll
    for (int m = 0; m < 4; m++) {
      int r = wm + m * 16 + (lane & 15);
      a[m] = __builtin_bit_cast(bf16x8,
          *reinterpret_cast<const uint4*>(&sm[(cur) * 4096 + (r * 4 + (uc ^ ((r >> 1) & 3))) * 8]));
    }
#pragma unroll
    for (int n = 0; n < 2; n++) {
      int r = wn + n * 16 + (lane & 15);
      b[n] = __builtin_bit_cast(bf16x8,
          *reinterpret_cast<const uint4*>(&sm[12288 + (cur) * 4096 + (r * 4 + (uc ^ ((r >> 1) & 3))) * 8]));
    }
#pragma unroll
    for (int m = 0; m < 4; m++)
#pragma unroll
      for (int n = 0; n < 2; n++)
        acc[m][n] = __builtin_amdgcn_mfma_f32_16x16x32_bf16(a[m], b[n], acc[m][n], 0, 0, 0);
  }

#pragma unroll
  for (int m = 0; m < 4; m++) {
#pragma unroll
    for (int rr = 0; rr < 4; rr++) {
      int row = wm + m * 16 + ((lane >> 4) << 2) + rr;
      if (row < rows) {
        int tok = toks[row];
        float* po = out + (size_t)tok * HDIM + n0 + wn + (lane & 15);
#pragma unroll
        for (int n = 0; n < 2; n++) atomicAdd(po + n * 16, acc[m][n][rr]);
      }
    }
  }
}

// ---------------- kernels -----------------------------------------------------
__global__ __launch_bounds__(512, 4) void g1a_kernel(
    const ushort_t* __restrict__ xslot, const ushort_t* __restrict__ w1p,
    const ushort_t* __restrict__ w3p, const float* __restrict__ wtls,
    const int* __restrict__ cnt, const int* __restrict__ offs,
    const int2* __restrict__ sched, ushort_t* __restrict__ hbufp) {
  extern __shared__ ushort_t sm[];
  int bid = blockIdx.x;                 // 288 blocks
  int xcd = bid & 7, j = bid >> 3;      // j 0..35
  gemm1_tile(xcd * 9 + (j >> 2), j & 3, sm, xslot, w1p, w3p, wtls, cnt, offs, sched, hbufp);
}

__global__ __launch_bounds__(512, 4) void g1b_g2a_kernel(
    const ushort_t* __restrict__ xslot, const ushort_t* __restrict__ w1p,
    const ushort_t* __restrict__ w3p, const float* __restrict__ wtls,
    const ushort_t* __restrict__ hbufp, const ushort_t* __restrict__ w2p,
    const int* __restrict__ slot2tok, const int* __restrict__ cnt,
    const int* __restrict__ offs, const int2* __restrict__ sched,
    ushort_t* __restrict__ hbufp_w, float* __restrict__ out) {
  extern __shared__ ushort_t sm[];
  int bid = blockIdx.x;                 // 576 blocks
  if (bid < 288) {
    int xcd = bid & 7, j = bid >> 3;
    gemm1_tile(xcd * 9 + (j >> 2), 4 + (j & 3), sm, xslot, w1p, w3p, wtls, cnt, offs, sched, hbufp_w);
  } else {
    int b2 = bid - 288;
    int xcd = b2 & 7, j = b2 >> 3;
    gemm2_tile<0>(xcd * 9 + (j >> 2), j & 3, sm, hbufp, w2p, slot2tok, cnt, offs, sched, out);
  }
}

__global__ __launch_bounds__(512, 6) void g2b_kernel(
    const ushort_t* __restrict__ hbufp, const ushort_t* __restrict__ w2p,
    const int* __restrict__ slot2tok, const int* __restrict__ cnt,
    const int* __restrict__ offs, const int2* __restrict__ sched,
    float* __restrict__ out) {
  extern __shared__ ushort_t sm[];
  int bid = blockIdx.x;                 // 288 blocks
  int xcd = bid & 7, j = bid >> 3;
  gemm2_tile<16>(xcd * 9 + (j >> 2), j & 3, sm, hbufp, w2p, slot2tok, cnt, offs, sched, out);
}

// ---------------- launch ----------------------------------------------------
extern "C" void kernel_launch(void* const* d_in, const int* in_sizes, int n_in,
                              void* d_out, int out_size, void* d_ws, size_t ws_size,
                              hipStream_t stream) {
  const float* x  = (const float*)d_in[0];
  const float* wg = (const float*)d_in[1];
  const float* bg = (const float*)d_in[2];
  const float* w1 = (const float*)d_in[3];
  const float* w3 = (const float*)d_in[4];
  const float* w2 = (const float*)d_in[5];
  float* out = (float*)d_out;
  char* ws = (char*)d_ws;

  int*   cnt     = (int*)(ws + 0);
  int*   offs    = (int*)(ws + 64);
  int2*  sched1  = (int2*)(ws + 128);
  int4*  selraw  = (int4*)(ws + 65536);
  int*   slot2tok= (int*)(ws + 131072);
  float* wtls    = (float*)(ws + 262144);
  ushort_t* xb    = (ushort_t*)(ws + (1ull << 20));
  ushort_t* xslot = (ushort_t*)(ws + (5ull << 20));
  ushort_t* w1p   = (ushort_t*)(ws + (14ull << 20));
  ushort_t* w3p   = (ushort_t*)(ws + (22ull << 20));
  ushort_t* w2p   = (ushort_t*)(ws + (30ull << 20));
  ushort_t* hbufp = (ushort_t*)(ws + (38ull << 20));

  pre_kernel<<<1024 + 12288 + 2048, 256, 0, stream>>>(x, wg, bg, selraw, xb,
                                                      w1, w3, w2, w1p, w3p, w2p, out);
  build_kernel<<<1, 256, 0, stream>>>(selraw, cnt, offs, sched1, slot2tok, wtls);
  xgather_kernel<<<512, 256, 0, stream>>>(xb, slot2tok, xslot);
  g1a_kernel<<<288, 512, 73728, stream>>>(xslot, w1p, w3p, wtls, cnt, offs, sched1, hbufp);
  g1b_g2a_kernel<<<576, 512, 73728, stream>>>(xslot, w1p, w3p, wtls, hbufp, w2p,
                                              slot2tok, cnt, offs, sched1, hbufp, out);
  g2b_kernel<<<288, 512, 49152, stream>>>(hbufp, w2p, slot2tok, cnt, offs, sched1, out);
}